// Round 5
// baseline (218.167 us; speedup 1.0000x reference)
//
#include <hip/hip_runtime.h>
#include <math.h>

#define NB       1025
#define FFTN     2048
#define HOP      512
#define NFRAMES  4000
#define BATCH    4
#define OUT_T    2047488          // (F-1)*hop + N - 2*half
#define R_HOPS   16
#define REG_PB   251              // ceil(4003/16)
#define ACC_N    (R_HOPS * HOP)   // 8192 floats = 32 KB
#define PI_F     3.14159265358979323846f
#define INV_M    (1.0f / 1024.0f)

typedef float vfloat4 __attribute__((ext_vector_type(4)));
typedef vfloat4 __attribute__((aligned(4))) vfloat4u;   // frame base is only 4B-aligned

__device__ __forceinline__ float2 cmul(float2 a, float2 b) {
    return make_float2(fmaf(a.x, b.x, -a.y * b.y), fmaf(a.x, b.y, a.y * b.x));
}
__device__ __forceinline__ float2 cadd(float2 a, float2 b){ return make_float2(a.x+b.x, a.y+b.y); }
__device__ __forceinline__ float2 csub(float2 a, float2 b){ return make_float2(a.x-b.x, a.y-b.y); }
__device__ __forceinline__ float2 caddi(float2 a, float2 b){ return make_float2(a.x-b.y, a.y+b.x); } // a + i*b
__device__ __forceinline__ float2 csubi(float2 a, float2 b){ return make_float2(a.x+b.y, a.y-b.x); } // a - i*b

template<int CTRL>
__device__ __forceinline__ float dppx(float v) {
    return __int_as_float(__builtin_amdgcn_mov_dpp(__float_as_int(v), CTRL, 0xF, 0xF, true));
}

// window_sumsquare at trimmed position p (boundary path, <=4 terms)
__device__ __forceinline__ float wsq_at(int p) {
    int u  = p + FFTN / 2;
    int fm = u >> 9;
    int n0 = u & 511;
    float wsq = 0.f;
    #pragma unroll
    for (int jj = 0; jj < 4; ++jj) {
        int fr = fm - jj;
        if (fr >= 0 && fr < NFRAMES) {
            int n = n0 + (jj << 9);
            float sw = __sinf((PI_F / (float)FFTN) * (float)n);
            float w  = sw * sw;
            wsq += w * w;
        }
    }
    const float tiny = 1.17549435e-38f;
    return (wsq > tiny) ? wsq : 1.0f;
}

// Wave-autonomous ISTFT: each wave computes full 1024-pt complex IFFTs
// (16 regs/lane x 64 lanes), no block barriers in the main loop.
// Block owns R_HOPS hops; 4 waves round-robin the overlapping frames and
// accumulate windowed samples into LDS via ds_add_f32.
__global__ __launch_bounds__(256) void istft_wave_kernel(
    const float* __restrict__ sr, const float* __restrict__ si,
    float* __restrict__ out)
{
    __shared__ float acc[ACC_N];

    const int tid = threadIdx.x;
    const int w   = tid >> 6;
    const int l   = tid & 63;
    const int blk = blockIdx.x;
    const int b   = blk / REG_PB;
    const int reg = blk - b * REG_PB;
    const int s0h = reg * R_HOPS;          // first hop owned (untrimmed units)

    #pragma unroll
    for (int q = 0; q < ACC_N / 256; ++q) acc[tid + q * 256] = 0.f;

    // ---- per-lane constants (reused across frames) ----
    const int m = (int)(__brev((unsigned)l) >> 26);   // bitrev6(lane) = output row
    float2 TW[5];
    float  sg[6];
    #pragma unroll
    for (int s = 0; s < 6; ++s) {
        const int d = 32 >> s;
        const bool q = (l & d) != 0;
        sg[s] = q ? -1.f : 1.f;
        if (s < 5) {
            float ang = (PI_F / (float)d) * (float)(l & (d - 1));
            float sv, cv; __sincosf(ang, &sv, &cv);
            TW[s] = q ? make_float2(cv, sv) : make_float2(1.f, 0.f);
        }
    }
    float2 twl; { float sv, cv; __sincosf((PI_F / 64.f) * (float)l, &sv, &cv); twl = make_float2(cv, sv); }
    float2 wm;  { float sv, cv; __sincosf((2.f * PI_F / 1024.f) * (float)m, &sv, &cv); wm = make_float2(cv, sv); }

    int f0 = s0h - 3;           if (f0 < 0)           f0 = 0;
    int f1 = s0h + R_HOPS - 1;  if (f1 > NFRAMES - 1) f1 = NFRAMES - 1;

    __syncthreads();   // acc zeroed

    for (int f = f0 + w; f <= f1; f += 4) {
        const size_t fb = ((size_t)b * NFRAMES + f) * NB;
        const float* __restrict__ xr = sr + fb;
        const float* __restrict__ xi = si + fb;
        const int la = 16 * l;
        const int mb = 1008 - la;   // aligned mirror block base (>=0 for l<=63)

        const vfloat4u* par = (const vfloat4u*)(xr + la);
        const vfloat4u* pai = (const vfloat4u*)(xi + la);
        const vfloat4u* pbr = (const vfloat4u*)(xr + mb);
        const vfloat4u* pbi = (const vfloat4u*)(xi + mb);
        vfloat4 ar4[4] = { par[0], par[1], par[2], par[3] };
        vfloat4 ai4[4] = { pai[0], pai[1], pai[2], pai[3] };
        vfloat4 br4[4] = { pbr[0], pbr[1], pbr[2], pbr[3] };
        vfloat4 bi4[4] = { pbi[0], pbi[1], pbi[2], pbi[3] };
        float X1024r = xr[1024];

        float ra[16], ia_[16], rm[16], im_[16];
        #pragma unroll
        for (int v = 0; v < 4; ++v) {
            #pragma unroll
            for (int c = 0; c < 4; ++c) {
                ra[v*4+c]  = ar4[v][c];
                ia_[v*4+c] = ai4[v][c];
                rm[v*4+c]  = br4[v][c];
                im_[v*4+c] = bi4[v][c];
            }
        }
        // mirror for k1=0: xr[1024-16l] = lane(l-1)'s rm[0]
        float m0r = __shfl_up(rm[0], 1);
        float m0i = __shfl_up(im_[0], 1);

        // ---- pack Hermitian spectrum into Z[k], k = 16*l + k1 ----
        float2 z[16];
        float2 twp = twl;  // e^{+i pi k/1024}, chained by e^{+i pi/1024}
        const float2 CE1 = make_float2(0.99999529380957617f, 0.0030679567629659762f);
        #pragma unroll
        for (int k1 = 0; k1 < 16; ++k1) {
            float arv = ra[k1], aiv = ia_[k1], brv, biv;
            if (k1 == 0) {
                brv = (l == 0) ? X1024r : m0r;
                biv = (l == 0) ? 0.f    : m0i;
                if (l == 0) aiv = 0.f;         // numpy irfft ignores imag of DC & Nyquist
            } else {
                brv = rm[16 - k1];
                biv = im_[16 - k1];
            }
            float Er = 0.5f * (arv + brv), Ei = 0.5f * (aiv - biv);
            float Dr = 0.5f * (arv - brv), Di = 0.5f * (aiv + biv);
            float Or = fmaf(Dr, twp.x, -Di * twp.y);
            float Oi = fmaf(Dr, twp.y,  Di * twp.x);
            z[k1] = make_float2(Er - Oi, Ei + Or);
            twp = cmul(twp, CE1);
        }

        // ---- cross-lane 64-pt IDFT over lanes (radix-2 DIF, 6 stages) ----
        // out lane l holds S[m], m = bitrev6(l)
        #pragma unroll
        for (int s = 0; s < 4; ++s) {          // d = 32,16,8,4 via shfl_xor
            const int d = 32 >> s;
            #pragma unroll
            for (int k1 = 0; k1 < 16; ++k1) {
                float xx = __shfl_xor(z[k1].x, d);
                float yy = __shfl_xor(z[k1].y, d);
                float2 pv = make_float2(fmaf(sg[s], z[k1].x, xx),
                                        fmaf(sg[s], z[k1].y, yy));
                z[k1] = cmul(pv, TW[s]);
            }
        }
        #pragma unroll
        for (int k1 = 0; k1 < 16; ++k1) {      // d = 2 via DPP quad_perm [2,3,0,1]
            float xx = dppx<0x4E>(z[k1].x);
            float yy = dppx<0x4E>(z[k1].y);
            float2 pv = make_float2(fmaf(sg[4], z[k1].x, xx),
                                    fmaf(sg[4], z[k1].y, yy));
            z[k1] = cmul(pv, TW[4]);
        }
        #pragma unroll
        for (int k1 = 0; k1 < 16; ++k1) {      // d = 1 via DPP quad_perm [1,0,3,2]
            float xx = dppx<0xB1>(z[k1].x);
            float yy = dppx<0xB1>(z[k1].y);
            z[k1] = make_float2(fmaf(sg[5], z[k1].x, xx),
                                fmaf(sg[5], z[k1].y, yy));
        }

        // ---- middle twiddle: z[k1] *= (e^{2 pi i m/1024})^{k1} ----
        {
            float2 t = wm;
            #pragma unroll
            for (int k1 = 1; k1 < 16; ++k1) {
                z[k1] = cmul(z[k1], t);
                if (k1 < 15) t = cmul(t, wm);
            }
        }

        // ---- in-register 16-pt IDFT over k1 -> g[n1] = G[m + 64*n1] ----
        float2 B[16];
        #pragma unroll
        for (int a = 0; a < 4; ++a) {
            float2 t0 = cadd(z[a],     z[a + 8]);
            float2 t1 = csub(z[a],     z[a + 8]);
            float2 t2 = cadd(z[a + 4], z[a + 12]);
            float2 t3 = csub(z[a + 4], z[a + 12]);
            B[a]      = cadd(t0, t2);    // r=0
            B[4 + a]  = caddi(t1, t3);   // r=1
            B[8 + a]  = csub(t0, t2);    // r=2
            B[12 + a] = csubi(t1, t3);   // r=3
        }
        const float2 W1 = make_float2( 0.92387953251128674f,  0.38268343236508978f);
        const float2 W2 = make_float2( 0.70710678118654757f,  0.70710678118654757f);
        const float2 W3 = make_float2( 0.38268343236508978f,  0.92387953251128674f);
        const float2 W4 = make_float2( 0.f, 1.f);
        const float2 W6 = make_float2(-0.70710678118654757f,  0.70710678118654757f);
        const float2 W9 = make_float2(-0.92387953251128674f, -0.38268343236508978f);
        B[5]  = cmul(B[5],  W1);  B[6]  = cmul(B[6],  W2);  B[7]  = cmul(B[7],  W3);
        B[9]  = cmul(B[9],  W2);  B[10] = cmul(B[10], W4);  B[11] = cmul(B[11], W6);
        B[13] = cmul(B[13], W3);  B[14] = cmul(B[14], W6);  B[15] = cmul(B[15], W9);

        float2 g[16];
        #pragma unroll
        for (int r = 0; r < 4; ++r) {
            float2 u0 = cadd(B[r*4 + 0], B[r*4 + 2]);
            float2 u1 = csub(B[r*4 + 0], B[r*4 + 2]);
            float2 u2 = cadd(B[r*4 + 1], B[r*4 + 3]);
            float2 u3 = csub(B[r*4 + 1], B[r*4 + 3]);
            g[r]      = cadd(u0, u2);
            g[r + 4]  = caddi(u1, u3);
            g[r + 8]  = csub(u0, u2);
            g[r + 12] = csubi(u1, u3);
        }

        // ---- window + LDS atomic overlap-add ----
        // x[2p]=Re g, x[2p+1]=Im g at p = m + 64*n1 -> frame pos t = 128*n1 + 2m + h
        const int off_f = (f - s0h) * HOP;   // float offset (multiple of 512)
        #pragma unroll
        for (int n1 = 0; n1 < 16; ++n1) {
            int lo = off_f + 128 * n1;       // 128-chunk: fully in or out of region
            if (lo >= 0 && lo + 128 <= ACC_N) {
                int   tt  = 128 * n1 + 2 * m;
                float s0v = __sinf((PI_F / 2048.f) * (float)tt);
                float s1v = __sinf((PI_F / 2048.f) * (float)(tt + 1));
                atomicAdd(&acc[lo + 2*m    ], g[n1].x * (s0v * s0v) * INV_M);
                atomicAdd(&acc[lo + 2*m + 1], g[n1].y * (s1v * s1v) * INV_M);
            }
        }
    }

    __syncthreads();   // all waves' accumulates done

    // ---- epilogue: divide by window_sumsquare, coalesced single write ----
    const int base_u = s0h * HOP;
    float* outb = out + (size_t)b * OUT_T;
    #pragma unroll
    for (int qq = 0; qq < ACC_N / 256; ++qq) {
        int i = tid + qq * 256;
        int p = base_u + i - FFTN / 2;
        if ((unsigned)p < (unsigned)OUT_T) {
            float invw = (p < 512 || p >= OUT_T - 512) ? (1.0f / wsq_at(p)) : (2.0f / 3.0f);
            outb[p] = acc[i] * invw;
        }
    }
}

extern "C" void kernel_launch(void* const* d_in, const int* in_sizes, int n_in,
                              void* d_out, int out_size, void* d_ws, size_t ws_size,
                              hipStream_t stream) {
    const float* sr = (const float*)d_in[0];
    const float* si = (const float*)d_in[1];
    float* out = (float*)d_out;
    istft_wave_kernel<<<BATCH * REG_PB, 256, 0, stream>>>(sr, si, out);
}

// Round 6
// 61.297 us; speedup vs baseline: 3.5592x; 3.5592x over previous
//
#include <hip/hip_runtime.h>
#include <math.h>

#define NB       1025
#define M        1024      // half-length complex FFT size
#define FFTN     2048
#define HOP      512
#define NFRAMES  4000
#define BATCH    4
#define OUT_T    2047488   // (F-1)*hop + N - 2*half
#define R_HOPS   8
#define REG_PB   501       // ceil(4003/8)
#define ACC_N    (R_HOPS * HOP)   // 4096 floats = 16 KB
#define PI_F     3.14159265358979323846f

__device__ __forceinline__ float2 cmul(float2 a, float2 b) {
    return make_float2(a.x*b.x - a.y*b.y, a.x*b.y + a.y*b.x);
}
// float2 bank-pair swizzle — b64 wave64 floor is 4 lanes/bank-pair
__device__ __forceinline__ int SW(int i) { return i ^ ((i >> 4) & 15); }

// window_sumsquare at trimmed position p (boundary path, <=4 terms)
__device__ __forceinline__ float wsq_at(int p) {
    int u  = p + FFTN / 2;
    int fm = u >> 9;
    int n0 = u & 511;
    float wsq = 0.f;
    #pragma unroll
    for (int jj = 0; jj < 4; ++jj) {
        int fr = fm - jj;
        if (fr >= 0 && fr < NFRAMES) {
            int n = n0 + (jj << 9);
            float sw = __sinf((PI_F / (float)FFTN) * (float)n);
            float w  = sw * sw;
            wsq += w * w;
        }
    }
    const float tiny = 1.17549435e-38f;
    return (wsq > tiny) ? wsq : 1.0f;
}

template<int ST>
__device__ __forceinline__ void stage(const float2* __restrict__ src,
                                      float2* __restrict__ dst, int j,
                                      float2 w1, float2 w2, float2 w3) {
    const int Ns = 1 << (2 * ST);
    float2 v0 = src[SW(j)];
    float2 v1 = src[SW(j + 256)];
    float2 v2 = src[SW(j + 512)];
    float2 v3 = src[SW(j + 768)];
    v1 = cmul(v1, w1); v2 = cmul(v2, w2); v3 = cmul(v3, w3);
    float2 t0 = make_float2(v0.x + v2.x, v0.y + v2.y);
    float2 t1 = make_float2(v0.x - v2.x, v0.y - v2.y);
    float2 t2 = make_float2(v1.x + v3.x, v1.y + v3.y);
    float2 t3 = make_float2(v1.x - v3.x, v1.y - v3.y);
    int jm = j & (Ns - 1);
    int idxD = ((j >> (2 * ST)) << (2 * ST + 2)) + jm;
    dst[SW(idxD         )] = make_float2(t0.x + t2.x, t0.y + t2.y);
    dst[SW(idxD +     Ns)] = make_float2(t1.x - t3.y, t1.y + t3.x);
    dst[SW(idxD + 2 * Ns)] = make_float2(t0.x - t2.x, t0.y - t2.y);
    dst[SW(idxD + 3 * Ns)] = make_float2(t1.x + t3.y, t1.y - t3.x);
}

// Region-owned OLA, pack+stage0 fused in registers, next-frame loads
// software-pipelined across the 4 remaining barriers.
__global__ __launch_bounds__(256) void istft_region_kernel(
    const float* __restrict__ sr, const float* __restrict__ si,
    float* __restrict__ out)
{
    __shared__ float2 buf0[M];
    __shared__ float2 buf1[M];
    __shared__ float2 acc2[ACC_N / 2];   // 16 KB accumulator

    const int blk = blockIdx.x;
    const int b   = blk / REG_PB;
    const int reg = blk - b * REG_PB;
    const int s0h = reg * R_HOPS;        // first hop owned (untrimmed units)
    const int j   = threadIdx.x;

    #pragma unroll
    for (int q = 0; q < ACC_N / 2 / 256; ++q)
        acc2[j + q * 256] = make_float2(0.f, 0.f);

    // ---- per-block precompute (reused across all frames) ----
    float2 tw_pack[4];
    #pragma unroll
    for (int kk = 0; kk < 4; ++kk) {
        int k = j + kk * 256;
        float s, c;
        __sincosf(PI_F * (float)k * (1.0f / (float)M), &s, &c);
        tw_pack[kk] = make_float2(c, s);
    }
    float2 w1s[4], w2s[4], w3s[4];       // stages 1..4
    #pragma unroll
    for (int st = 1; st <= 4; ++st) {
        int Ns = 1 << (2 * st);
        int jm = j & (Ns - 1);
        float ang = (0.5f * PI_F / (float)Ns) * (float)jm;
        float s1, c1;
        __sincosf(ang, &s1, &c1);
        float2 w1 = make_float2(c1, s1);
        w1s[st-1] = w1;
        w2s[st-1] = cmul(w1, w1);
        w3s[st-1] = cmul(w2s[st-1], w1);
    }
    float wreg[4][2];                    // hann^2... hann(t)/M for t = 2n, 2n+1
    #pragma unroll
    for (int q = 0; q < 4; ++q) {
        int n = j + q * 256;
        #pragma unroll
        for (int h = 0; h < 2; ++h) {
            int t = 2 * n + h;
            float swv = __sinf((PI_F / (float)FFTN) * (float)t);
            wreg[q][h] = swv * swv * (1.0f / 1024.0f);
        }
    }

    int f0 = s0h - 3;           if (f0 < 0)           f0 = 0;
    int f1 = s0h + R_HOPS - 1;  if (f1 > NFRAMES - 1) f1 = NFRAMES - 1;

    __syncthreads();   // acc zeroed

    // ---- preload frame f0's spectrum slice (16 scalar loads, coalesced) ----
    float car[4], cai[4], cbr[4], cbi[4];
    {
        const size_t fb = ((size_t)b * NFRAMES + f0) * NB;
        const float* __restrict__ xr = sr + fb;
        const float* __restrict__ xi = si + fb;
        #pragma unroll
        for (int kk = 0; kk < 4; ++kk) {
            int k  = j + kk * 256;
            int mk = M - k;
            car[kk] = xr[k];  cai[kk] = xi[k];
            cbr[kk] = xr[mk]; cbi[kk] = xi[mk];
        }
    }

    for (int f = f0; f <= f1; ++f) {
        // ---- pack + stage0 fused (registers -> buf0) ----
        {
            float2 z[4];
            #pragma unroll
            for (int kk = 0; kk < 4; ++kk) {
                float arv = car[kk], aiv = cai[kk];
                float brv = cbr[kk], biv = cbi[kk];
                if (kk == 0 && j == 0) { aiv = 0.f; biv = 0.f; }  // DC/Nyquist imag ignored
                float Er = 0.5f * (arv + brv), Ei = 0.5f * (aiv - biv);
                float Dr = 0.5f * (arv - brv), Di = 0.5f * (aiv + biv);
                float2 t = tw_pack[kk];
                float Or = Dr * t.x - Di * t.y;
                float Oi = Dr * t.y + Di * t.x;
                z[kk] = make_float2(Er - Oi, Ei + Or);
            }
            float2 t0 = make_float2(z[0].x + z[2].x, z[0].y + z[2].y);
            float2 t1 = make_float2(z[0].x - z[2].x, z[0].y - z[2].y);
            float2 t2 = make_float2(z[1].x + z[3].x, z[1].y + z[3].y);
            float2 t3 = make_float2(z[1].x - z[3].x, z[1].y - z[3].y);
            buf0[SW(4*j    )] = make_float2(t0.x + t2.x, t0.y + t2.y);
            buf0[SW(4*j + 1)] = make_float2(t1.x - t3.y, t1.y + t3.x);
            buf0[SW(4*j + 2)] = make_float2(t0.x - t2.x, t0.y - t2.y);
            buf0[SW(4*j + 3)] = make_float2(t1.x + t3.y, t1.y - t3.x);
        }

        // ---- prefetch next frame's spectrum (waited after stage 4) ----
        float nar[4], nai[4], nbr[4], nbi[4];
        {
            int fn = (f < f1) ? (f + 1) : f1;
            const size_t fb = ((size_t)b * NFRAMES + fn) * NB;
            const float* __restrict__ xr = sr + fb;
            const float* __restrict__ xi = si + fb;
            #pragma unroll
            for (int kk = 0; kk < 4; ++kk) {
                int k  = j + kk * 256;
                int mk = M - k;
                nar[kk] = xr[k];  nai[kk] = xi[k];
                nbr[kk] = xr[mk]; nbi[kk] = xi[mk];
            }
        }

        __syncthreads();
        stage<1>(buf0, buf1, j, w1s[0], w2s[0], w3s[0]);
        __syncthreads();
        stage<2>(buf1, buf0, j, w1s[1], w2s[1], w3s[1]);
        __syncthreads();
        stage<3>(buf0, buf1, j, w1s[2], w2s[2], w3s[2]);
        __syncthreads();

        // ---- stage 4 in registers from buf1: g at n = j+q*256 ----
        float2 v0 = buf1[SW(j)];
        float2 v1 = buf1[SW(j + 256)];
        float2 v2 = buf1[SW(j + 512)];
        float2 v3 = buf1[SW(j + 768)];
        v1 = cmul(v1, w1s[3]);
        v2 = cmul(v2, w2s[3]);
        v3 = cmul(v3, w3s[3]);
        float2 t0 = make_float2(v0.x + v2.x, v0.y + v2.y);
        float2 t1 = make_float2(v0.x - v2.x, v0.y - v2.y);
        float2 t2 = make_float2(v1.x + v3.x, v1.y + v3.y);
        float2 t3 = make_float2(v1.x - v3.x, v1.y - v3.y);
        float2 g0 = make_float2(t0.x + t2.x, t0.y + t2.y);   // n = j
        float2 g1 = make_float2(t1.x - t3.y, t1.y + t3.x);   // n = j+256
        float2 g2 = make_float2(t0.x - t2.x, t0.y - t2.y);   // n = j+512
        float2 g3 = make_float2(t1.x + t3.y, t1.y - t3.x);   // n = j+768

        // ---- windowed accumulate into region acc ----
        int ofs2 = (HOP / 2) * (f - s0h);
        {
            int i2 = ofs2 + j;
            if ((unsigned)i2 < (unsigned)(ACC_N / 2)) {
                float2 a = acc2[i2];
                a.x += g0.x * wreg[0][0];  a.y += g0.y * wreg[0][1];
                acc2[i2] = a;
            }
            i2 = ofs2 + j + 256;
            if ((unsigned)i2 < (unsigned)(ACC_N / 2)) {
                float2 a = acc2[i2];
                a.x += g1.x * wreg[1][0];  a.y += g1.y * wreg[1][1];
                acc2[i2] = a;
            }
            i2 = ofs2 + j + 512;
            if ((unsigned)i2 < (unsigned)(ACC_N / 2)) {
                float2 a = acc2[i2];
                a.x += g2.x * wreg[2][0];  a.y += g2.y * wreg[2][1];
                acc2[i2] = a;
            }
            i2 = ofs2 + j + 768;
            if ((unsigned)i2 < (unsigned)(ACC_N / 2)) {
                float2 a = acc2[i2];
                a.x += g3.x * wreg[3][0];  a.y += g3.y * wreg[3][1];
                acc2[i2] = a;
            }
        }

        // rotate prefetched regs into current (register moves, unrolled)
        #pragma unroll
        for (int kk = 0; kk < 4; ++kk) {
            car[kk] = nar[kk]; cai[kk] = nai[kk];
            cbr[kk] = nbr[kk]; cbi[kk] = nbi[kk];
        }
    }

    __syncthreads();   // all frames' accumulates done

    // ---- epilogue: divide by window_sumsquare, write once, coalesced ----
    const float* accf = (const float*)acc2;
    const int base_u = s0h * HOP;
    float* outb = out + (size_t)b * OUT_T;
    #pragma unroll
    for (int q = 0; q < ACC_N / 256; ++q) {
        int i = j + q * 256;
        int p = base_u + i - FFTN / 2;
        if ((unsigned)p < (unsigned)OUT_T) {
            float invw = (p < 512 || p >= OUT_T - 512) ? (1.0f / wsq_at(p)) : (2.0f / 3.0f);
            outb[p] = accf[i] * invw;
        }
    }
}

extern "C" void kernel_launch(void* const* d_in, const int* in_sizes, int n_in,
                              void* d_out, int out_size, void* d_ws, size_t ws_size,
                              hipStream_t stream) {
    const float* sr = (const float*)d_in[0];
    const float* si = (const float*)d_in[1];
    float* out = (float*)d_out;
    istft_region_kernel<<<BATCH * REG_PB, 256, 0, stream>>>(sr, si, out);
}